// Round 12
// baseline (119.514 us; speedup 1.0000x reference)
//
#include <hip/hip_runtime.h>
#include <stdint.h>

#define M_DIM 4096
#define N_DIM 4096
#define K_DIM 4096

typedef int i32x4 __attribute__((ext_vector_type(4)));

// ---- Kernel 1 (fused): blocks 0..4095: x per-row quant; blocks 4096..5119: wmax ----
__global__ void prep_kernel(const float* __restrict__ w,
                            const float* __restrict__ x,
                            unsigned int* __restrict__ out_bits,
                            char* __restrict__ xq,
                            float* __restrict__ xsinv) {
    __shared__ float sred[4];
    if (blockIdx.x < 4096) {
        // ---- x -> int8, per-row scale; xsinv[row] = rowmax/127 ----
        const int row = blockIdx.x;
        const int t = threadIdx.x;
        const float4* xr = (const float4*)(x + (size_t)row * K_DIM);
        float4 v[4];
        float m = 0.f;
        #pragma unroll
        for (int i = 0; i < 4; ++i) {
            v[i] = xr[t * 4 + i];
            m = fmaxf(m, fmaxf(fmaxf(fabsf(v[i].x), fabsf(v[i].y)),
                               fmaxf(fabsf(v[i].z), fabsf(v[i].w))));
        }
        for (int off = 32; off > 0; off >>= 1) m = fmaxf(m, __shfl_xor(m, off));
        if ((t & 63) == 0) sred[t >> 6] = m;
        __syncthreads();
        m = fmaxf(fmaxf(fmaxf(sred[0], sred[1]), fmaxf(sred[2], sred[3])), 1e-30f);
        if (t == 0) xsinv[row] = m * (1.0f / 127.0f);
        const float scale = 127.0f / m;
        int4 o;
        int* op = (int*)&o;
        #pragma unroll
        for (int i = 0; i < 4; ++i) {
            int a = (int)rintf(v[i].x * scale);
            int b = (int)rintf(v[i].y * scale);
            int c = (int)rintf(v[i].z * scale);
            int d = (int)rintf(v[i].w * scale);
            op[i] = (a & 0xff) | ((b & 0xff) << 8) | ((c & 0xff) << 16) | (d << 24);
        }
        *(int4*)(xq + (size_t)row * K_DIM + t * 16) = o;
    } else {
        // ---- wmax = max|W| -> uint bits, one atomic per block ----
        int tid = (blockIdx.x - 4096) * blockDim.x + threadIdx.x;
        const int stride = 1024 * 256;
        const int n4 = (N_DIM * K_DIM) / 4;
        const float4* w4 = (const float4*)w;
        float m = 0.f;
        for (int i = tid; i < n4; i += stride) {
            float4 a = w4[i];
            m = fmaxf(m, fmaxf(fmaxf(fabsf(a.x), fabsf(a.y)), fmaxf(fabsf(a.z), fabsf(a.w))));
        }
        for (int off = 32; off > 0; off >>= 1) m = fmaxf(m, __shfl_xor(m, off));
        if ((threadIdx.x & 63) == 0) sred[threadIdx.x >> 6] = m;
        __syncthreads();
        if (threadIdx.x == 0) {
            m = fmaxf(fmaxf(sred[0], sred[1]), fmaxf(sred[2], sred[3]));
            atomicMax(out_bits, __float_as_uint(m));  // |w|>=0: uint order == float order
        }
    }
}

// ---- Kernel 2: W -> int8 (trunc, exact reference grid) ----
__global__ void wquant_kernel(const float* __restrict__ w,
                              const unsigned int* __restrict__ mb,
                              int* __restrict__ wq4, int n4) {
    const float wscale = 127.0f / __uint_as_float(mb[0]);
    int tid = blockIdx.x * blockDim.x + threadIdx.x;
    int stride = gridDim.x * blockDim.x;
    const float4* w4 = (const float4*)w;
    for (int i = tid; i < n4; i += stride) {
        float4 a = w4[i];
        int w0 = (int)fminf(fmaxf(truncf(a.x * wscale), -127.f), 127.f);
        int w1 = (int)fminf(fmaxf(truncf(a.y * wscale), -127.f), 127.f);
        int w2 = (int)fminf(fmaxf(truncf(a.z * wscale), -127.f), 127.f);
        int w3 = (int)fminf(fmaxf(truncf(a.w * wscale), -127.f), 127.f);
        wq4[i] = (w0 & 0xff) | ((w1 & 0xff) << 8) | ((w2 & 0xff) << 16) | (w3 << 24);
    }
}

// ---- Kernel 3: 256x256 i8 GEMM, BK=64, 4-slot LDS ring (4x32KB=128KB) with
// CROSS-BARRIER REGISTER PREFETCH: tile T enters with Q00/Q01 operands (af0,bf0,bf1)
// already in regs (loaded from slot T&3 during T-1); refills for T+1 read slot (T+1)&3
// right after each frag's last use. MFMA starts at cycle 0 of each tile.
// Slot: A [256 rows][64B] @+0 (16KB), B @+16384. Swizzle: chunk ^= (row>>1)&3
// (uniform 8 lanes/bank-quad = conflict-free; stage pre-swizzles global source).
#define BAR()   __builtin_amdgcn_s_barrier()
#define FENCE() __builtin_amdgcn_sched_barrier(0)

#define MFMA_I8(ACC, AF, BF) \
    asm("v_mfma_i32_16x16x64_i8 %0, %1, %2, %0" : "+v"(ACC) : "v"(AF), "v"(BF))

__global__ __launch_bounds__(512, 2) void gemm_i8(
    const char* __restrict__ A,
    const char* __restrict__ B,
    const unsigned int* __restrict__ mb,
    const float* __restrict__ xsinv,
    const float* __restrict__ bias,
    float* __restrict__ C)
{
    __shared__ __align__(16) char sM[131072];   // 4 slots x 32KB

    int bid = (blockIdx.x & 7) * 32 + (blockIdx.x >> 3);   // XCD-bijective (nwg=256)
    const int bm = bid >> 4;
    const int bn = bid & 15;

    const int t    = threadIdx.x;
    const int wave = t >> 6;
    const int lane = t & 63;
    const int wm   = wave >> 2;     // 0..1
    const int wn   = wave & 3;      // 0..3

    i32x4 acc[2][2][4][2] = {};     // [h][g][mi][ni]

    // Read bases. Row r = (16-mult) + (lane&15); byte = r*64 + ((lane>>4)^((r>>1)&3))*16,
    // and (r>>1)&3 == (lane>>1)&3 for all our 16-aligned row offsets.
    const int chunk = (((lane >> 4) ^ ((lane >> 1) & 3)) << 4);
    const int lbA = ((lane & 15) << 6) + chunk + wm * 4096;           // + h*8192 + mi*1024
    const int lbB = ((lane & 15) << 6) + chunk + wn * 2048 + 16384;   // + g*8192 + ni*1024

    // Staging: thread t -> row t>>2 (0..127), chunk t&3; pre-swizzled source chunk
    // cch = (t&3) ^ ((row>>1)&3) = (t&3) ^ ((t>>3)&3). LDS dest wave-uniform.
    const int srow = t >> 2;
    const int cch  = (t & 3) ^ ((t >> 3) & 3);
    const char* Abase = A + (size_t)(bm * 256 + srow) * K_DIM + cch * 16;
    const char* Bbase = B + (size_t)(bn * 256 + srow) * K_DIM + cch * 16;
    const int wave_lds = wave * 1024;   // uniform; HW adds lane*16

    // Stage one matrix tile (256 rows x 64B) of A(REG=0)/B(REG=16384): 2 gload/thread.
#define STAGE2(SRC, REG, KT, SLOT) do {                                                 \
        _Pragma("unroll") for (int i = 0; i < 2; ++i) {                                 \
            const char* _s = SRC + (size_t)(i * 128) * K_DIM + ((KT) << 6);             \
            char* _d = sM + (SLOT) * 32768 + (REG) + i * 8192 + wave_lds;               \
            __builtin_amdgcn_global_load_lds(                                           \
                (const __attribute__((address_space(1))) void*)_s,                      \
                (__attribute__((address_space(3))) void*)_d, 16, 0, 0);                 \
        }                                                                               \
    } while(0)

#define LDA(H, SLOT, AF)                                                                \
        _Pragma("unroll") for (int mi = 0; mi < 4; ++mi)                                \
            AF[mi] = *(const i32x4*)(sM + (SLOT)*32768 + (H)*8192 + mi*1024 + lbA);

#define LDB(G, SLOT, BF)                                                                \
        _Pragma("unroll") for (int ni = 0; ni < 2; ++ni)                                \
            BF[ni] = *(const i32x4*)(sM + (SLOT)*32768 + (G)*8192 + ni*1024 + lbB);

    // one C-quadrant x K=64: 8 MFMA (independent accs)
#define MMAQ(H, G, AF, BF)                                                              \
        _Pragma("unroll") for (int mi = 0; mi < 4; ++mi)                                \
        _Pragma("unroll") for (int ni = 0; ni < 2; ++ni)                                \
            MFMA_I8(acc[H][G][mi][ni], AF[mi], BF[ni]);

    i32x4 af0[4], af1[4], bf0[2], bf1[2];

    // One K-tile T: CUR=T&3 (compute), NXT=(T+1)&3 (refill P), STG=(T+2)&3 (stage KN).
#define TILE(CUR, NXT, STG, KN) do {                                                    \
        LDA(1, CUR, af1);                        /* 4 reads: Q1x operands */            \
        STAGE2(Abase, 0,     KN, STG);                                                  \
        STAGE2(Bbase, 16384, KN, STG);           /* 4 gload_lds */                      \
        FENCE();                                                                        \
        __builtin_amdgcn_s_setprio(1);                                                  \
        MMAQ(0, 0, af0, bf0);                    /* P in regs: starts at cycle 0 */     \
        MMAQ(0, 1, af0, bf1);                                                           \
        __builtin_amdgcn_s_setprio(0);                                                  \
        FENCE();                                                                        \
        LDA(0, NXT, af0);                        /* refill af0 (last use: Q01) */       \
        FENCE();                                                                        \
        __builtin_amdgcn_s_setprio(1);                                                  \
        MMAQ(1, 0, af1, bf0);                                                           \
        __builtin_amdgcn_s_setprio(0);                                                  \
        FENCE();                                                                        \
        LDB(0, NXT, bf0);                        /* refill bf0 (last use: Q10) */       \
        FENCE();                                                                        \
        __builtin_amdgcn_s_setprio(1);                                                  \
        MMAQ(1, 1, af1, bf1);                                                           \
        __builtin_amdgcn_s_setprio(0);                                                  \
        FENCE();                                                                        \
        LDB(1, NXT, bf1);                        /* refill bf1 (last use: Q11) */       \
        asm volatile("s_waitcnt vmcnt(0)");      /* stages for STG landed */            \
        BAR();                                                                          \
        FENCE();                                                                        \
    } while(0)

    // Prologue: stage tiles 0,1 -> slots 0,1; preload P(tile0) from slot 0.
    STAGE2(Abase, 0,     0, 0);
    STAGE2(Bbase, 16384, 0, 0);
    STAGE2(Abase, 0,     1, 1);
    STAGE2(Bbase, 16384, 1, 1);
    asm volatile("s_waitcnt vmcnt(4)");   // tile0 landed; tile1 still in flight
    BAR();
    FENCE();
    LDA(0, 0, af0);
    LDB(0, 0, bf0);
    LDB(1, 0, bf1);
    FENCE();

    for (int it = 0; it < 16; ++it) {
        const int T = it * 4;
        TILE(0, 1, 2, (T + 2) & 63);
        TILE(1, 2, 3, (T + 3) & 63);
        TILE(2, 3, 0, (T + 4) & 63);
        TILE(3, 0, 1, (T + 5) & 63);
    }

    const float wdq = __uint_as_float(mb[0]) * (1.0f / 127.0f);

    // Epilogue: D layout (m89): col = lane&15, row = (lane>>4)*4 + reg.
    // C = acc * (wdq * xsinv[row]) + bias[col]
    #pragma unroll
    for (int h = 0; h < 2; ++h)
    #pragma unroll
    for (int mi = 0; mi < 4; ++mi) {
        const int grow0 = bm * 256 + h * 128 + wm * 64 + mi * 16 + (lane >> 4) * 4;
        float rs[4];
        #pragma unroll
        for (int rg = 0; rg < 4; ++rg) rs[rg] = xsinv[grow0 + rg] * wdq;
        #pragma unroll
        for (int g = 0; g < 2; ++g)
        #pragma unroll
        for (int ni = 0; ni < 2; ++ni) {
            const int gcol = bn * 256 + g * 128 + wn * 32 + ni * 16 + (lane & 15);
            const float bv = bias[gcol];
            #pragma unroll
            for (int rg = 0; rg < 4; ++rg)
                C[(size_t)(grow0 + rg) * N_DIM + gcol] =
                    (float)acc[h][g][mi][ni][rg] * rs[rg] + bv;
        }
    }

#undef STAGE2
#undef LDA
#undef LDB
#undef MMAQ
#undef TILE
}

extern "C" void kernel_launch(void* const* d_in, const int* in_sizes, int n_in,
                              void* d_out, int out_size, void* d_ws, size_t ws_size,
                              hipStream_t stream) {
    const float* x    = (const float*)d_in[0];   // [4096, 4096]
    const float* w    = (const float*)d_in[1];   // [4096, 4096]
    const float* bias = (const float*)d_in[2];   // [4096]
    float* out = (float*)d_out;

    unsigned int* maxbits = (unsigned int*)d_ws;            // [0]=wmax bits
    float* xsinv = (float*)((char*)d_ws + 256);             // [4096]
    char*  xq    = (char*)d_ws + 32768;                     // 16 MB
    char*  wq    = (char*)d_ws + 32768 + (size_t)M_DIM * K_DIM;

    hipMemsetAsync(d_ws, 0, 8, stream);

    const int n4 = (N_DIM * K_DIM) / 4;
    prep_kernel<<<4096 + 1024, 256, 0, stream>>>(w, x, maxbits, xq, xsinv);
    wquant_kernel<<<2048, 256, 0, stream>>>(w, maxbits, (int*)wq, n4);

    const int grid = (M_DIM / 256) * (N_DIM / 256);  // 256
    gemm_i8<<<grid, 512, 0, stream>>>(xq, wq, maxbits, xsinv, bias, out);
}

// Round 13
// 101.006 us; speedup vs baseline: 1.1832x; 1.1832x over previous
//
#include <hip/hip_runtime.h>
#include <stdint.h>

#define M_DIM 4096
#define N_DIM 4096
#define K_DIM 4096

typedef int i32x4 __attribute__((ext_vector_type(4)));

// ---- Kernel 1: blocks 0..2047: W partial max -> wpmax[b]; blocks 2048..4095:
// 2 x-rows each: rowmax -> xsinv, quant -> xq (single pass, no atomics) ----
__global__ void prep1_kernel(const float* __restrict__ w,
                             const float* __restrict__ x,
                             float* __restrict__ wpmax,
                             char* __restrict__ xq,
                             float* __restrict__ xsinv) {
    __shared__ float sred[4];
    const int t = threadIdx.x;
    if (blockIdx.x < 2048) {
        // ---- W partial max (grid-stride), one value per block ----
        int tid = blockIdx.x * 256 + t;
        const int stride = 2048 * 256;
        const int n4 = (N_DIM * K_DIM) / 4;
        const float4* w4 = (const float4*)w;
        float m = 0.f;
        for (int i = tid; i < n4; i += stride) {
            float4 a = w4[i];
            m = fmaxf(m, fmaxf(fmaxf(fabsf(a.x), fabsf(a.y)), fmaxf(fabsf(a.z), fabsf(a.w))));
        }
        for (int off = 32; off > 0; off >>= 1) m = fmaxf(m, __shfl_xor(m, off));
        if ((t & 63) == 0) sred[t >> 6] = m;
        __syncthreads();
        if (t == 0)
            wpmax[blockIdx.x] = fmaxf(fmaxf(sred[0], sred[1]), fmaxf(sred[2], sred[3]));
    } else {
        // ---- x -> int8, per-row scale; 2 rows per block ----
        const int rbase = (blockIdx.x - 2048) * 2;
        #pragma unroll
        for (int r = 0; r < 2; ++r) {
            const int row = rbase + r;
            const float4* xr = (const float4*)(x + (size_t)row * K_DIM);
            float4 v[4];
            float m = 0.f;
            #pragma unroll
            for (int i = 0; i < 4; ++i) {
                v[i] = xr[t * 4 + i];
                m = fmaxf(m, fmaxf(fmaxf(fabsf(v[i].x), fabsf(v[i].y)),
                                   fmaxf(fabsf(v[i].z), fabsf(v[i].w))));
            }
            for (int off = 32; off > 0; off >>= 1) m = fmaxf(m, __shfl_xor(m, off));
            if ((t & 63) == 0) sred[t >> 6] = m;
            __syncthreads();
            m = fmaxf(fmaxf(fmaxf(sred[0], sred[1]), fmaxf(sred[2], sred[3])), 1e-30f);
            if (t == 0) xsinv[row] = m * (1.0f / 127.0f);
            const float scale = 127.0f / m;
            int4 o;
            int* op = (int*)&o;
            #pragma unroll
            for (int i = 0; i < 4; ++i) {
                int a = (int)rintf(v[i].x * scale);
                int b = (int)rintf(v[i].y * scale);
                int c = (int)rintf(v[i].z * scale);
                int d = (int)rintf(v[i].w * scale);
                op[i] = (a & 0xff) | ((b & 0xff) << 8) | ((c & 0xff) << 16) | (d << 24);
            }
            *(int4*)(xq + (size_t)row * K_DIM + t * 16) = o;
            __syncthreads();   // sred WAR before next row
        }
    }
}

// ---- Kernel 2: every block reduces wpmax[0..2047] (deterministic, L2-hot) -> wscale;
// grid-stride W -> int8 (trunc, exact reference grid); block 0 stores wdq scalar ----
__global__ void prep2_kernel(const float* __restrict__ w,
                             const float* __restrict__ wpmax,
                             int* __restrict__ wq4,
                             float* __restrict__ wdq_out) {
    __shared__ float sred[4];
    const int t = threadIdx.x;
    float m = 0.f;
    #pragma unroll
    for (int i = 0; i < 8; ++i) m = fmaxf(m, wpmax[t * 8 + i]);
    for (int off = 32; off > 0; off >>= 1) m = fmaxf(m, __shfl_xor(m, off));
    if ((t & 63) == 0) sred[t >> 6] = m;
    __syncthreads();
    const float maxv = fmaxf(fmaxf(sred[0], sred[1]), fmaxf(sred[2], sred[3]));
    const float wscale = 127.0f / maxv;
    if (blockIdx.x == 0 && t == 0) *wdq_out = maxv * (1.0f / 127.0f);

    int tid = blockIdx.x * 256 + t;
    const int stride = 2048 * 256;
    const int n4 = (N_DIM * K_DIM) / 4;
    const float4* w4 = (const float4*)w;
    for (int i = tid; i < n4; i += stride) {
        float4 a = w4[i];
        int w0 = (int)fminf(fmaxf(truncf(a.x * wscale), -127.f), 127.f);
        int w1 = (int)fminf(fmaxf(truncf(a.y * wscale), -127.f), 127.f);
        int w2 = (int)fminf(fmaxf(truncf(a.z * wscale), -127.f), 127.f);
        int w3 = (int)fminf(fmaxf(truncf(a.w * wscale), -127.f), 127.f);
        wq4[i] = (w0 & 0xff) | ((w1 & 0xff) << 8) | ((w2 & 0xff) << 16) | (w3 << 24);
    }
}

// ---- Kernel 3: 256x256 i8 GEMM (R6-verbatim: 1 barrier/K-tile, all-LDS, upfront
// grouped reads -> compiler counted-lgkm overlap). LDS 128KB: A dbuf @0/32K, B @64K/96K.
// Swizzle byte ^= (row&7)<<4 both-sides. mfma_i32_16x16x64_i8 kk-outer.
#define BAR()   __builtin_amdgcn_s_barrier()
#define FENCE() __builtin_amdgcn_sched_barrier(0)

#define MFMA_I8(ACC, AF, BF) \
    asm("v_mfma_i32_16x16x64_i8 %0, %1, %2, %0" : "+v"(ACC) : "v"(AF), "v"(BF))

__global__ __launch_bounds__(512, 2) void gemm_i8(
    const char* __restrict__ A,
    const char* __restrict__ B,
    const float* __restrict__ wdqp,
    const float* __restrict__ xsinv,
    const float* __restrict__ bias,
    float* __restrict__ C)
{
    __shared__ __align__(16) char sM[131072];

    int bid = (blockIdx.x & 7) * 32 + (blockIdx.x >> 3);   // XCD-bijective (nwg=256)
    const int bm = bid >> 4;
    const int bn = bid & 15;

    const int t    = threadIdx.x;
    const int wave = t >> 6;
    const int lane = t & 63;
    const int wm   = wave >> 2;     // 0..1
    const int wn   = wave & 3;      // 0..3

    i32x4 acc[2][2][4][2] = {};     // [h][g][mi][ni]

    // LDS-read bases (swizzle folded: row&7 == lane&7 for all row-blocks used)
    const int chunk = (((lane >> 4) << 4) ^ ((lane & 7) << 4));
    const int lbA0 = ((lane & 15) << 7) + chunk + wm * 8192;
    const int lbA1 = lbA0 ^ 64;
    const int lbB0 = ((lane & 15) << 7) + chunk + wn * 4096 + 65536;
    const int lbB1 = lbB0 ^ 64;

    // Staging: thread t owns linear LDS slot t*16 (+8192 for 2nd 64-row block);
    // source chunk pre-swizzled so LDS[row][c] = SRC[row][c^(row&7)].
    const int srow = t >> 3;
    const int cch  = (t & 7) ^ (srow & 7);
    const char* Abase = A + (size_t)(bm * 256 + srow) * K_DIM + cch * 16;
    const char* Bbase = B + (size_t)(bn * 256 + srow) * K_DIM + cch * 16;
    const int wave_lds = wave * 1024;   // wave-uniform dest; HW adds lane*16

#define STAGE(SRC, REG, H, KT, BUF) do {                                                \
        const char* _s = SRC + (H) * (128 * K_DIM) + ((KT) << 7);                       \
        char* _d = sM + (REG) + (BUF) * 32768 + (H) * 16384 + wave_lds;                 \
        __builtin_amdgcn_global_load_lds(                                               \
            (const __attribute__((address_space(1))) void*)_s,                          \
            (__attribute__((address_space(3))) void*)_d, 16, 0, 0);                     \
        __builtin_amdgcn_global_load_lds(                                               \
            (const __attribute__((address_space(1))) void*)(_s + (size_t)64 * K_DIM),   \
            (__attribute__((address_space(3))) void*)(_d + 8192), 16, 0, 0);            \
    } while(0)

#define LDA(H, BUF, AF) do {                                                            \
        _Pragma("unroll") for (int mi = 0; mi < 4; ++mi) {                              \
            AF[mi][0] = *(const i32x4*)(sM + (BUF)*32768 + (H)*16384 + mi*2048 + lbA0); \
            AF[mi][1] = *(const i32x4*)(sM + (BUF)*32768 + (H)*16384 + mi*2048 + lbA1); \
        }                                                                               \
    } while(0)

#define LDB(G, BUF, BF) do {                                                            \
        _Pragma("unroll") for (int ni = 0; ni < 2; ++ni) {                              \
            BF[ni][0] = *(const i32x4*)(sM + (BUF)*32768 + (G)*16384 + ni*2048 + lbB0); \
            BF[ni][1] = *(const i32x4*)(sM + (BUF)*32768 + (G)*16384 + ni*2048 + lbB1); \
        }                                                                               \
    } while(0)

    // one C-quadrant x K=128: 16 MFMA, kk-outer (8 indep accs between acc reuse)
#define MMAQ(H, G, AF, BF)                                                              \
        _Pragma("unroll") for (int kk = 0; kk < 2; ++kk)                                \
        _Pragma("unroll") for (int mi = 0; mi < 4; ++mi)                                \
        _Pragma("unroll") for (int ni = 0; ni < 2; ++ni)                                \
            MFMA_I8(acc[H][G][mi][ni], AF[mi][kk], BF[ni][kk]);

    // One K-tile: reads from BUF, stages K-tile KN into OBUF, 64 MFMA, 1 barrier.
#define TILE(BUF, OBUF, KN) do {                                                        \
        LDA(0, BUF, af0); LDB(0, BUF, bf0);      /* 12 reads for Q(0,0) */              \
        FENCE();                                                                        \
        LDB(1, BUF, bf1);                        /* 4 reads */                          \
        STAGE(Abase, 0,     0, KN, OBUF);                                               \
        STAGE(Bbase, 65536, 0, KN, OBUF);                                               \
        STAGE(Abase, 0,     1, KN, OBUF);                                               \
        STAGE(Bbase, 65536, 1, KN, OBUF);                                               \
        LDA(1, BUF, af1);                        /* 8 reads */                          \
        FENCE();                                                                        \
        __builtin_amdgcn_s_setprio(1);                                                  \
        MMAQ(0, 0, af0, bf0);                                                           \
        MMAQ(0, 1, af0, bf1);                                                           \
        MMAQ(1, 1, af1, bf1);                                                           \
        MMAQ(1, 0, af1, bf0);                                                           \
        __builtin_amdgcn_s_setprio(0);                                                  \
        asm volatile("s_waitcnt vmcnt(0)");      /* stages issued ~2600cy ago */        \
        BAR();                                                                          \
        FENCE();                                                                        \
    } while(0)

    // Prologue: stage tile 0 -> buf0 only.
    STAGE(Abase, 0,     0, 0, 0);
    STAGE(Bbase, 65536, 0, 0, 0);
    STAGE(Abase, 0,     1, 0, 0);
    STAGE(Bbase, 65536, 1, 0, 0);
    asm volatile("s_waitcnt vmcnt(0)");
    BAR();
    FENCE();

    i32x4 af0[4][2], af1[4][2], bf0[2][2], bf1[2][2];

    for (int it = 0; it < 16; ++it) {
        TILE(0, 1, (2 * it + 1) & 31);
        TILE(1, 0, (2 * it + 2) & 31);
    }

    const float wdq = *wdqp;

    // Epilogue: D layout (m89): col = lane&15, row = (lane>>4)*4 + reg.
    // C = acc * (wdq * xsinv[row]) + bias[col]
    #pragma unroll
    for (int h = 0; h < 2; ++h)
    #pragma unroll
    for (int mi = 0; mi < 4; ++mi) {
        const int grow0 = bm * 256 + h * 128 + wm * 64 + mi * 16 + (lane >> 4) * 4;
        float rs[4];
        #pragma unroll
        for (int rg = 0; rg < 4; ++rg) rs[rg] = xsinv[grow0 + rg] * wdq;
        #pragma unroll
        for (int g = 0; g < 2; ++g)
        #pragma unroll
        for (int ni = 0; ni < 2; ++ni) {
            const int gcol = bn * 256 + g * 128 + wn * 32 + ni * 16 + (lane & 15);
            const float bv = bias[gcol];
            #pragma unroll
            for (int rg = 0; rg < 4; ++rg)
                C[(size_t)(grow0 + rg) * N_DIM + gcol] =
                    (float)acc[h][g][mi][ni][rg] * rs[rg] + bv;
        }
    }

#undef STAGE
#undef LDA
#undef LDB
#undef MMAQ
#undef TILE
}

extern "C" void kernel_launch(void* const* d_in, const int* in_sizes, int n_in,
                              void* d_out, int out_size, void* d_ws, size_t ws_size,
                              hipStream_t stream) {
    const float* x    = (const float*)d_in[0];   // [4096, 4096]
    const float* w    = (const float*)d_in[1];   // [4096, 4096]
    const float* bias = (const float*)d_in[2];   // [4096]
    float* out = (float*)d_out;

    float* wpmax = (float*)d_ws;                            // [2048] partial maxima
    float* wdqp  = (float*)((char*)d_ws + 8192);            // [1] wmax/127
    float* xsinv = (float*)((char*)d_ws + 8448);            // [4096]
    char*  xq    = (char*)d_ws + 32768;                     // 16 MB
    char*  wq    = (char*)d_ws + 32768 + (size_t)M_DIM * K_DIM;

    prep1_kernel<<<4096, 256, 0, stream>>>(w, x, wpmax, xq, xsinv);
    prep2_kernel<<<2048, 256, 0, stream>>>(w, wpmax, (int*)wq, wdqp);

    const int grid = (M_DIM / 256) * (N_DIM / 256);  // 256
    gemm_i8<<<grid, 512, 0, stream>>>(xq, wq, wdqp, xsinv, bias, out);
}